// Round 3
// baseline (349.696 us; speedup 1.0000x reference)
//
#include <hip/hip_runtime.h>

#define N_NODES 4096
#define C_CH 16
#define HW 256
#define NODE_ELEMS 4096   // 16*16*16
#define E_EDGES 16384

// edge_index is int64 in the reference; harness may hand us int32 or raw int64.
// If int64 (little-endian, values < 4096), the odd 32-bit words of the first
// 16 entries are all zero. Probability of false positive with real int32
// indices: (1/4096)^16 ~ 0.
__device__ inline bool detect_i64(const int* p) {
    int z = 0;
#pragma unroll
    for (int i = 0; i < 16; i++) z += (p[2 * i + 1] == 0) ? 1 : 0;
    return z == 16;
}

__device__ inline int eidx(const int* p, bool i64, int i) {
    return i64 ? p[2 * i] : p[i];
}

__global__ void zero_kernel(int* deg) {
    int i = blockIdx.x * blockDim.x + threadIdx.x;
    if (i < N_NODES) deg[i] = 0;
}

__global__ void hist_kernel(const int* ei, int* deg) {
    bool i64 = detect_i64(ei);
    int e = blockIdx.x * blockDim.x + threadIdx.x;
    if (e < E_EDGES) {
        int d = eidx(ei, i64, E_EDGES + e);
        atomicAdd(&deg[d], 1);
    }
}

// 4096 values, one block of 1024 threads, 4 elems/thread, Hillis-Steele.
__global__ void scan_kernel(const int* deg, int* off, int* cursor) {
    __shared__ int part[1024];
    int t = threadIdx.x;
    int b = t * 4;
    int s0 = deg[b], s1 = deg[b + 1], s2 = deg[b + 2], s3 = deg[b + 3];
    int sum = s0 + s1 + s2 + s3;
    part[t] = sum;
    __syncthreads();
    for (int d = 1; d < 1024; d <<= 1) {
        int v = (t >= d) ? part[t - d] : 0;
        __syncthreads();
        part[t] += v;
        __syncthreads();
    }
    int start = part[t] - sum;  // exclusive prefix of this thread's group
    off[b] = start;             cursor[b] = start;
    off[b + 1] = start + s0;           cursor[b + 1] = off[b + 1];
    off[b + 2] = start + s0 + s1;      cursor[b + 2] = off[b + 2];
    off[b + 3] = start + s0 + s1 + s2; cursor[b + 3] = off[b + 3];
}

__global__ void scatter_kernel(const int* ei, int* cursor, int* esrc) {
    bool i64 = detect_i64(ei);
    int e = blockIdx.x * blockDim.x + threadIdx.x;
    if (e < E_EDGES) {
        int s = eidx(ei, i64, e);
        int d = eidx(ei, i64, E_EDGES + e);
        int pos = atomicAdd(&cursor[d], 1);
        esrc[pos] = s;
    }
}

// One block per node. Stage x[n] and agg[n] in zero-padded LDS tiles, then
// compute out = relu(conv3x3(x,Ww)+Wb + conv3x3(agg,Bw)+Bb).
__global__ __launch_bounds__(256) void fused_kernel(
    const float* __restrict__ x,
    const float* __restrict__ Ww, const float* __restrict__ Wb,
    const float* __restrict__ Bw, const float* __restrict__ Bb,
    const int* __restrict__ off, const int* __restrict__ deg,
    const int* __restrict__ esrc,
    float* __restrict__ out)
{
    __shared__ float xs[16][18][18];
    __shared__ float as_[16][18][18];
    int n = blockIdx.x;
    int t = threadIdx.x;
    int h = t >> 4, w = t & 15;

    // zero entire LDS tiles (covers the padding borders)
    {
        float* l0 = &xs[0][0][0];
        float* l1 = &as_[0][0][0];
        for (int i = t; i < 16 * 18 * 18; i += 256) { l0[i] = 0.f; l1[i] = 0.f; }
    }

    const float* xn = x + (size_t)n * NODE_ELEMS;
    int o = off[n], dg = deg[n];

    // gather-sum source images into registers (thread t owns spatial pos t,
    // one element per channel: i = k*256 + t is contiguous across lanes)
    float aacc[16];
#pragma unroll
    for (int k = 0; k < 16; k++) aacc[k] = 0.f;
    for (int j = 0; j < dg; j++) {
        const float* xsrc = x + (size_t)esrc[o + j] * NODE_ELEMS;
#pragma unroll
        for (int k = 0; k < 16; k++) aacc[k] += xsrc[k * HW + t];
    }
    float scale = 1.0f / (float)(dg > 1 ? dg : 1);

    __syncthreads();  // zeroing done before interior writes
#pragma unroll
    for (int k = 0; k < 16; k++) {
        xs[k][h + 1][w + 1]  = xn[k * HW + t];
        as_[k][h + 1][w + 1] = aacc[k] * scale;
    }
    __syncthreads();

    float acc[16];
#pragma unroll
    for (int co = 0; co < 16; co++) acc[co] = Wb[co] + Bb[co];

    // weights are wave-uniform -> scalar loads; inner: 2 ds_read + 32 v_fma
#pragma unroll 1
    for (int c = 0; c < 16; c++) {
#pragma unroll
        for (int dy = 0; dy < 3; dy++) {
#pragma unroll
            for (int dx = 0; dx < 3; dx++) {
                float xv = xs[c][h + dy][w + dx];
                float av = as_[c][h + dy][w + dx];
                int wb = c * 9 + dy * 3 + dx;
#pragma unroll
                for (int co = 0; co < 16; co++) {
                    acc[co] = fmaf(xv, Ww[co * 144 + wb], acc[co]);
                    acc[co] = fmaf(av, Bw[co * 144 + wb], acc[co]);
                }
            }
        }
    }

    float* on = out + (size_t)n * NODE_ELEMS;
#pragma unroll
    for (int co = 0; co < 16; co++) {
        float v = acc[co];
        on[co * HW + t] = v > 0.f ? v : 0.f;
    }
}

extern "C" void kernel_launch(void* const* d_in, const int* in_sizes, int n_in,
                              void* d_out, int out_size, void* d_ws, size_t ws_size,
                              hipStream_t stream) {
    const float* x  = (const float*)d_in[0];
    const int*   ei = (const int*)d_in[1];
    const float* Ww = (const float*)d_in[2];
    const float* Wb = (const float*)d_in[3];
    const float* Bw = (const float*)d_in[4];
    const float* Bb = (const float*)d_in[5];
    float* out = (float*)d_out;

    int* deg    = (int*)d_ws;
    int* off    = deg + N_NODES;
    int* cursor = off + N_NODES;
    int* esrc   = cursor + N_NODES;

    zero_kernel<<<(N_NODES + 255) / 256, 256, 0, stream>>>(deg);
    hist_kernel<<<(E_EDGES + 255) / 256, 256, 0, stream>>>(ei, deg);
    scan_kernel<<<1, 1024, 0, stream>>>(deg, off, cursor);
    scatter_kernel<<<(E_EDGES + 255) / 256, 256, 0, stream>>>(ei, cursor, esrc);
    fused_kernel<<<N_NODES, 256, 0, stream>>>(x, Ww, Wb, Bw, Bb, off, deg, esrc, out);
}

// Round 4
// 78.941 us; speedup vs baseline: 4.4298x; 4.4298x over previous
//
#include <hip/hip_runtime.h>

#define N_NODES 4096
#define HW 256
#define NODE_ELEMS 4096
#define E_EDGES 16384
#define PITCH 24            // channel-dim pad (elements): 48B row pitch, 16B-aligned, bank-friendly
#define TILE_E (18*18*PITCH)

typedef __attribute__((ext_vector_type(8))) short short8;
typedef __attribute__((ext_vector_type(4))) float f32x4;

__device__ inline unsigned short f2bf(float f) {
    union { float f; unsigned int u; } a; a.f = f;
    unsigned int r = a.u + 0x7fffu + ((a.u >> 16) & 1u);   // RNE
    return (unsigned short)(r >> 16);
}

// ---- edge-index dtype hedge (int64 vs int32) ----
__device__ inline bool detect_i64(const int* p) {
    int z = 0;
#pragma unroll
    for (int i = 0; i < 16; i++) z += (p[2 * i + 1] == 0) ? 1 : 0;
    return z == 16;
}
__device__ inline int eidx(const int* p, bool i64, int i) { return i64 ? p[2 * i] : p[i]; }

__global__ void zero_kernel(int* deg) {
    int i = blockIdx.x * blockDim.x + threadIdx.x;
    if (i < N_NODES) deg[i] = 0;
}

__global__ void hist_kernel(const int* ei, int* deg) {
    bool i64 = detect_i64(ei);
    int e = blockIdx.x * blockDim.x + threadIdx.x;
    if (e < E_EDGES) atomicAdd(&deg[eidx(ei, i64, E_EDGES + e)], 1);
}

__global__ void scan_kernel(const int* deg, int* off, int* cursor) {
    __shared__ int part[1024];
    int t = threadIdx.x;
    int b = t * 4;
    int s0 = deg[b], s1 = deg[b + 1], s2 = deg[b + 2], s3 = deg[b + 3];
    int sum = s0 + s1 + s2 + s3;
    part[t] = sum;
    __syncthreads();
    for (int d = 1; d < 1024; d <<= 1) {
        int v = (t >= d) ? part[t - d] : 0;
        __syncthreads();
        part[t] += v;
        __syncthreads();
    }
    int start = part[t] - sum;
    off[b] = start;                    cursor[b] = start;
    off[b + 1] = start + s0;           cursor[b + 1] = off[b + 1];
    off[b + 2] = start + s0 + s1;      cursor[b + 2] = off[b + 2];
    off[b + 3] = start + s0 + s1 + s2; cursor[b + 3] = off[b + 3];
}

__global__ void scatter_kernel(const int* ei, int* cursor, int* esrc) {
    bool i64 = detect_i64(ei);
    int e = blockIdx.x * blockDim.x + threadIdx.x;
    if (e < E_EDGES) {
        int s = eidx(ei, i64, e);
        int d = eidx(ei, i64, E_EDGES + e);
        esrc[atomicAdd(&cursor[d], 1)] = s;
    }
}

// Repack weights: w2[co*288 + k], k = part*144 + tap*16 + c  (part0=Ww, part1=Bw)
__global__ void w2prep_kernel(const float* Ww, const float* Bw, unsigned short* w2) {
    int i = blockIdx.x * blockDim.x + threadIdx.x;
    if (i >= 16 * 288) return;
    int co = i / 288, k = i % 288;
    int part = (k >= 144) ? 1 : 0;
    int kk = k - part * 144;
    int tap = kk >> 4, c = kk & 15;
    const float* src = part ? Bw : Ww;
    w2[i] = f2bf(src[co * 144 + c * 9 + tap]);
}

// One block (256 thr = 4 waves) per node.
// LDS: x-tile and agg-tile, channel-last [18][18][PITCH] bf16, zero borders.
// GEMM: D[16co x 256pos] = W2[16 x 288] * im2col[288 x 256] via mfma 16x16x32 bf16.
__global__ __launch_bounds__(256) void fused_mfma(
    const float* __restrict__ x,
    const unsigned short* __restrict__ w2,
    const float* __restrict__ Wb, const float* __restrict__ Bb,
    const int* __restrict__ off, const int* __restrict__ deg,
    const int* __restrict__ esrc,
    float* __restrict__ out)
{
    __shared__ __align__(16) unsigned short xs[TILE_E];
    __shared__ __align__(16) unsigned short as_[TILE_E];

    int n = blockIdx.x;
    int t = threadIdx.x;
    int h = t >> 4, w = t & 15;

    // zero both tiles (covers padding borders + channel pad)
    {
        uint4 z = make_uint4(0, 0, 0, 0);
        uint4* p0 = (uint4*)xs;
        uint4* p1 = (uint4*)as_;
        for (int i = t; i < TILE_E / 8; i += 256) { p0[i] = z; p1[i] = z; }
    }

    const float* xn = x + (size_t)n * NODE_ELEMS;
    int o = off[n], dg = deg[n];

    // gather-sum sources (coalesced: lane-consecutive t)
    float aacc[16];
#pragma unroll
    for (int k = 0; k < 16; k++) aacc[k] = 0.f;
    for (int j = 0; j < dg; j++) {
        const float* xsrc = x + (size_t)esrc[o + j] * NODE_ELEMS;
#pragma unroll
        for (int k = 0; k < 16; k++) aacc[k] += xsrc[k * HW + t];
    }
    float scale = 1.0f / (float)(dg > 1 ? dg : 1);

    __syncthreads();  // zeroing complete

    // stage interiors channel-last as bf16 (2x ds_write_b128 per tile)
    {
        int pos = ((h + 1) * 18 + (w + 1)) * PITCH;
        union { unsigned short u[8]; uint4 v; } pk;
#pragma unroll
        for (int half = 0; half < 2; half++) {
#pragma unroll
            for (int j = 0; j < 8; j++) pk.u[j] = f2bf(xn[(half * 8 + j) * HW + t]);
            *(uint4*)&xs[pos + half * 8] = pk.v;
        }
#pragma unroll
        for (int half = 0; half < 2; half++) {
#pragma unroll
            for (int j = 0; j < 8; j++) pk.u[j] = f2bf(aacc[half * 8 + j] * scale);
            *(uint4*)&as_[pos + half * 8] = pk.v;
        }
    }
    __syncthreads();

    // ---- MFMA compute ----
    int lane = t & 63, wv = t >> 6;
    int g = lane >> 4;        // k-block group
    int m16 = lane & 15;      // A row (co) / B col (spatial w)
    int gg = g >> 1;          // tap-within-step select
    int c8 = (g & 1) * 8;     // channel half

    // A-fragments: weights, k = 32*s + g*8 + j, held in regs for all tiles
    short8 afr[9];
#pragma unroll
    for (int s = 0; s < 9; s++)
        afr[s] = *(const short8*)&w2[m16 * 288 + s * 32 + g * 8];

    // per-s B base pointers (lane-constant): tile select + tap offset + channel half
    const unsigned short* pb[9];
#pragma unroll
    for (int s = 0; s < 9; s++) {
        int kt = 2 * s + gg;                  // global tap index 0..17
        const unsigned short* base = (kt < 9) ? xs : as_;
        int tap = (kt < 9) ? kt : kt - 9;
        int dy = tap / 3, dx = tap % 3;
        pb[s] = base + (dy * 18 + dx) * PITCH + c8;
    }

    // bias init: D row m = g*4 + r
    f32x4 binit;
#pragma unroll
    for (int r = 0; r < 4; r++) binit[r] = Wb[g * 4 + r] + Bb[g * 4 + r];

    float* on = out + (size_t)n * NODE_ELEMS;

#pragma unroll
    for (int tt = 0; tt < 4; tt++) {
        int T = wv * 4 + tt;                          // spatial row = N-tile
        int rowbase = (T * 18 + m16) * PITCH;         // (+1,+1 border folded into pb? no:)
        // positions are interior: row T maps to LDS row T+dy (dy=0..2 covers T..T+2),
        // col m16+dx; border offset: interior starts at [1][1], and conv taps span
        // [T .. T+2] x [w .. w+2] in padded coords exactly -> base (T*18 + m16)*PITCH.
        f32x4 a = binit;
#pragma unroll
        for (int s = 0; s < 9; s++) {
            short8 bfr = *(const short8*)(pb[s] + rowbase);
            a = __builtin_amdgcn_mfma_f32_16x16x32_bf16(afr[s], bfr, a, 0, 0, 0);
        }
#pragma unroll
        for (int r = 0; r < 4; r++) {
            float v = a[r];
            on[(g * 4 + r) * HW + T * 16 + m16] = v > 0.f ? v : 0.f;
        }
    }
}

extern "C" void kernel_launch(void* const* d_in, const int* in_sizes, int n_in,
                              void* d_out, int out_size, void* d_ws, size_t ws_size,
                              hipStream_t stream) {
    const float* x  = (const float*)d_in[0];
    const int*   ei = (const int*)d_in[1];
    const float* Ww = (const float*)d_in[2];
    const float* Wb = (const float*)d_in[3];
    const float* Bw = (const float*)d_in[4];
    const float* Bb = (const float*)d_in[5];
    float* out = (float*)d_out;

    int* deg    = (int*)d_ws;
    int* off    = deg + N_NODES;
    int* cursor = off + N_NODES;
    int* esrc   = cursor + N_NODES;
    unsigned short* w2 = (unsigned short*)(esrc + E_EDGES);   // 16*288 bf16, 16B-aligned

    zero_kernel<<<(N_NODES + 255) / 256, 256, 0, stream>>>(deg);
    hist_kernel<<<(E_EDGES + 255) / 256, 256, 0, stream>>>(ei, deg);
    scan_kernel<<<1, 1024, 0, stream>>>(deg, off, cursor);
    scatter_kernel<<<(E_EDGES + 255) / 256, 256, 0, stream>>>(ei, cursor, esrc);
    w2prep_kernel<<<(16 * 288 + 255) / 256, 256, 0, stream>>>(Ww, Bw, w2);
    fused_mfma<<<N_NODES, 256, 0, stream>>>(x, w2, Wb, Bb, off, deg, esrc, out);
}